// Round 7
// baseline (217.379 us; speedup 1.0000x reference)
//
#include <hip/hip_runtime.h>
#include <hip/hip_bf16.h>

// Florence2VisionWindowAttention on MI355X (gfx950), bf16-MFMA pipeline.
// R6: (1) QKV epilogue scatters to attn-friendly layout: Q,K=[wh][tok][32],
//     V^T=[wh][32][176] (pads zeroed by pad_clear); (2) both GEMMs 128^2
//     ring-2 single-barrier, 32KB LDS, 4 blocks/CU; (3) attn v2: coalesced
//     Q/K loads + V^T staged via global_load_lds (no scalar transpose).

typedef unsigned short u16;
typedef unsigned int u32;
typedef __attribute__((ext_vector_type(4))) float f32x4;
typedef __attribute__((ext_vector_type(8))) short short8;

#define MFMA16(a, b, c) __builtin_amdgcn_mfma_f32_16x16x32_bf16(a, b, c, 0, 0, 0)
#define AS1 __attribute__((address_space(1)))
#define AS3 __attribute__((address_space(3)))

constexpr size_t QTOT = (size_t)2048 * 4608;   // Q region elems (= K region)
constexpr int VSTR = 176;                      // V^T row stride (u16)
constexpr size_t VWH = 32 * VSTR;              // V^T elems per (win,head)

__device__ __forceinline__ u16 f2b(float f) {
  __hip_bfloat16 h = __float2bfloat16(f);
  return *reinterpret_cast<u16*>(&h);
}

// ---------------- prep: gather x into window order + fp32->bf16 ----------------
__global__ void prep_x_kernel(const float* __restrict__ x, u16* __restrict__ xw) {
  int c = blockIdx.x * 256 + threadIdx.x;
  int r = c >> 6;
  int colb = (c & 63) << 3;
  int win = r / 144, tok = r - win * 144;
  int b = win >> 4, wh = (win >> 2) & 3, ww = win & 3;
  int i = tok / 12, j = tok - i * 12;
  const float* src = x + ((size_t)((b * 48 + wh * 12 + i) * 48 + ww * 12 + j)) * 512 + colb;
  float4 a0 = *(const float4*)(src);
  float4 a1 = *(const float4*)(src + 4);
  short8 o;
  o[0] = (short)f2b(a0.x); o[1] = (short)f2b(a0.y); o[2] = (short)f2b(a0.z); o[3] = (short)f2b(a0.w);
  o[4] = (short)f2b(a1.x); o[5] = (short)f2b(a1.y); o[6] = (short)f2b(a1.z); o[7] = (short)f2b(a1.w);
  *reinterpret_cast<short8*>(xw + (size_t)r * 512 + colb) = o;
}

// ---------------- prep: weight transpose K x N -> N x K bf16 ----------------
__global__ void prep_wt_kernel(const float* __restrict__ w, u16* __restrict__ wt,
                               int K, int N) {
  int t = blockIdx.x * 256 + threadIdx.x;
  int nchunks = N >> 3;
  if (t >= K * nchunks) return;
  int k = t / nchunks;
  int n0 = (t - k * nchunks) << 3;
  const float* src = w + (size_t)k * N + n0;
  float4 a0 = *(const float4*)(src);
  float4 a1 = *(const float4*)(src + 4);
  float v[8] = {a0.x, a0.y, a0.z, a0.w, a1.x, a1.y, a1.z, a1.w};
#pragma unroll
  for (int j = 0; j < 8; j++) wt[(size_t)(n0 + j) * K + k] = f2b(v[j]);
}

// ---------------- pad_clear: zero V^T pad cols [144,176) ----------------
__global__ void pad_clear_kernel(u16* __restrict__ vs) {
  int wh = blockIdx.x;
  int t = threadIdx.x;            // 128 threads
  int d = t >> 2, c = 144 + (t & 3) * 8;
  short8 z = {0, 0, 0, 0, 0, 0, 0, 0};
  *reinterpret_cast<short8*>(vs + (size_t)wh * VWH + d * VSTR + c) = z;
}

// ---------------- GEMM core: C = A(MxK) * BT(NxK)^T + bias ----------------
// 128^2 tile, 4 waves (2x2), BK=32, 2-slot LDS ring (32KB), single barrier
// per K-tile. Per-iter: gate vmcnt(0)+barrier -> frag ds_reads -> stage t+1
// (opposite slot; its prior readers drained: MFMA issue implies lgkmcnt
// drain, and all waves passed the top barrier) -> MFMA cluster.
// Swizzle: linear 16B-slot = logical ^ ((row>>1)&3); staged via pre-swizzled
// global source, read with same XOR (2-way conflicts = free).
// EPI: 0 = bf16 row-major; 1 = fp32 + window_reverse; 2 = QKV scatter to
//      Q[wh][tok][32], K[wh][tok][32], V^T[wh][d][176].
template <int BM, int BN, int WM, int WN, int EPI>
__device__ __forceinline__ void gemm_impl(
    const u16* __restrict__ A, const u16* __restrict__ BT,
    const float* __restrict__ bias,
    u16* __restrict__ outb, float* __restrict__ outf,
    int M, int N, int K) {
  constexpr int MF = BM / WM / 16;
  constexpr int NF = BN / WN / 16;
  constexpr int ASLOT = BM * 32;
  constexpr int BSLOT = BN * 32;
  __shared__ __align__(16) u16 sA[2 * ASLOT];
  __shared__ __align__(16) u16 sB[2 * BSLOT];

  const int tid = threadIdx.x;
  const int wave = tid >> 6;
  const int lane = tid & 63;
  const int wm = wave / WN;
  const int wn = wave % WN;
  const int l15 = lane & 15;
  const int lhi = lane >> 4;

  // XCD-bijective block swizzle (grid % 8 == 0 for all our launches)
  const int nwg = gridDim.x;
  const int cpx = nwg >> 3;
  const int bid = (blockIdx.x & 7) * cpx + (blockIdx.x >> 3);
  const int nbn = N / BN;
  const int bn = bid % nbn;
  const int bm = bid / nbn;

  f32x4 acc[MF][NF];
  const f32x4 fzero = {0.f, 0.f, 0.f, 0.f};
#pragma unroll
  for (int i = 0; i < MF; i++)
#pragma unroll
    for (int j = 0; j < NF; j++) acc[i][j] = fzero;

  const int srow = lane >> 2;                                // row in 16-row chunk
  const int scol = (((lane & 3) ^ ((lane >> 3) & 3)) << 3);  // pre-swizzled col
  const int rcol = ((lhi ^ ((l15 >> 1) & 3)) << 3);          // swizzled read col

  const u16* Ab = A + (size_t)(bm * BM) * K;
  const u16* Bb = BT + (size_t)(bn * BN) * K;
  const int nt = K >> 5;

  auto stage = [&](int l, int tt) {
    const int slot = tt & 1;
    const int kk = tt << 5;
    if (l < 2) {
      const int c = wave * 2 + l;
      __builtin_amdgcn_global_load_lds(
          (const AS1 u32*)(Ab + (size_t)(c * 16 + srow) * K + kk + scol),
          (AS3 u32*)(&sA[slot * ASLOT + c * 512]), 16, 0, 0);
    } else {
      const int c = wave * 2 + (l - 2);
      __builtin_amdgcn_global_load_lds(
          (const AS1 u32*)(Bb + (size_t)(c * 16 + srow) * K + kk + scol),
          (AS3 u32*)(&sB[slot * BSLOT + c * 512]), 16, 0, 0);
    }
  };

#pragma unroll
  for (int l = 0; l < 4; ++l) stage(l, 0);

  for (int t = 0; t < nt; ++t) {
    const int cur = t & 1;

    asm volatile("s_waitcnt vmcnt(0)");
    __builtin_amdgcn_sched_barrier(0);
    __builtin_amdgcn_s_barrier();
    __builtin_amdgcn_sched_barrier(0);

    const u16* pA = &sA[cur * ASLOT];
    const u16* pB = &sB[cur * BSLOT];

    short8 af[MF], bfr[NF];
#pragma unroll
    for (int m = 0; m < MF; ++m)
      af[m] = *reinterpret_cast<const short8*>(
          pA + (wm * (MF * 16) + m * 16 + l15) * 32 + rcol);
#pragma unroll
    for (int n = 0; n < NF; ++n)
      bfr[n] = *reinterpret_cast<const short8*>(
          pB + (wn * (NF * 16) + n * 16 + l15) * 32 + rcol);
    __builtin_amdgcn_sched_barrier(0);

    if (t + 1 < nt) {
#pragma unroll
      for (int l = 0; l < 4; ++l) stage(l, t + 1);
    }
    __builtin_amdgcn_sched_barrier(0);

    __builtin_amdgcn_s_setprio(1);
#pragma unroll
    for (int m = 0; m < MF; ++m)
#pragma unroll
      for (int n = 0; n < NF; ++n)
        acc[m][n] = MFMA16(af[m], bfr[n], acc[m][n]);
    __builtin_amdgcn_s_setprio(0);
  }

  // epilogue
#pragma unroll
  for (int i = 0; i < MF; ++i) {
    const int row0 = bm * BM + wm * (MF * 16) + i * 16 + lhi * 4;
#pragma unroll
    for (int j = 0; j < NF; ++j) {
      const int col = bn * BN + wn * (NF * 16) + j * 16 + l15;
      const float bv = bias[col];
#pragma unroll
      for (int r = 0; r < 4; ++r) {
        float v = acc[i][j][r] + bv;
        const int row = row0 + r;
        if (EPI == 0) {
          outb[(size_t)row * N + col] = f2b(v);
        } else if (EPI == 1) {
          int win = row / 144, tok = row - win * 144;
          int b = win >> 4, wh = (win >> 2) & 3, ww = win & 3;
          int ii = tok / 12, jj = tok - ii * 12;
          size_t o = ((size_t)b * 2304 + (wh * 12 + ii) * 48 + (ww * 12 + jj)) * 512 + col;
          outf[o] = v;
        } else {
          // QKV scatter: col -> {Q,K,V}, head, d ; row -> win, tok
          int dg = col & 511;
          int typ = col >> 9;
          int head = dg >> 5, d = dg & 31;
          int win = row / 144, tok = row - win * 144;
          int wh = win * 16 + head;
          u16 bv16 = f2b(v);
          if (typ == 0)
            outb[(size_t)wh * 4608 + tok * 32 + d] = bv16;
          else if (typ == 1)
            outb[QTOT + (size_t)wh * 4608 + tok * 32 + d] = bv16;
          else
            outb[2 * QTOT + (size_t)wh * VWH + d * VSTR + tok] = bv16;
        }
      }
    }
  }
}

__global__ __launch_bounds__(256, 4) void qkv_gemm(
    const u16* __restrict__ A, const u16* __restrict__ BT,
    const float* __restrict__ bias, u16* __restrict__ outb,
    int M, int N, int K) {
  gemm_impl<128, 128, 2, 2, 2>(A, BT, bias, outb, nullptr, M, N, K);
}

__global__ __launch_bounds__(256, 4) void proj_gemm(
    const u16* __restrict__ A, const u16* __restrict__ BT,
    const float* __restrict__ bias, float* __restrict__ outf,
    int M, int N, int K) {
  gemm_impl<128, 128, 2, 2, 1>(A, BT, bias, nullptr, outf, M, N, K);
}

// ---------------- fused window attention v2 ----------------
// One block per (win,head) = wh, 192 threads = 3 waves, 48 q-rows/wave.
// Q,K read coalesced from [wh][tok][32]; V^T staged via global_load_lds
// from [wh][32][176] (pads pre-zeroed). No-max softmax.
__global__ __launch_bounds__(192) void attn_kernel(const u16* __restrict__ qkvs,
                                                   u16* __restrict__ outb) {
  constexpr int PSTR = 168;
  __shared__ __align__(16) u16 sVT[32 * VSTR];      // 11264 B
  __shared__ __align__(16) u16 sP[3 * 16 * PSTR];
  const int tid = threadIdx.x;
  const int wave = tid >> 6;
  const int lane = tid & 63;
  const int l15 = lane & 15;
  const int lhi = lane >> 4;
  const int wh = blockIdx.x;
  const int win = wh >> 4;
  const int head = wh & 15;
  const u16* Q = qkvs + (size_t)wh * 4608;
  const u16* Kp = qkvs + QTOT + (size_t)wh * 4608;
  const u16* V = qkvs + 2 * QTOT + (size_t)wh * VWH;
  constexpr float SC2 = 0.25509915922608635f;       // (1/sqrt(32)) * log2(e)
  const f32x4 fzero = {0.f, 0.f, 0.f, 0.f};

  // stage V^T (32x176 u16 = 11 KB) linearly: 11 wave-instrs of 1KB
#pragma unroll
  for (int i = 0; i < 4; ++i) {
    const int c = wave * 4 + i;                     // wave-uniform
    if (c < 11) {
      __builtin_amdgcn_global_load_lds(
          (const AS1 u32*)(V + c * 512 + lane * 8),
          (AS3 u32*)(&sVT[c * 512]), 16, 0, 0);
    }
  }

  // coalesced Q/K fragment loads
  short8 qa[3];
#pragma unroll
  for (int mt = 0; mt < 3; mt++) {
    int row = wave * 48 + mt * 16 + l15;
    qa[mt] = *reinterpret_cast<const short8*>(Q + row * 32 + lhi * 8);
  }
  short8 kb[9];
#pragma unroll
  for (int nt = 0; nt < 9; nt++) {
    int ctok = nt * 16 + l15;
    kb[nt] = *reinterpret_cast<const short8*>(Kp + ctok * 32 + lhi * 8);
  }

  // zero own-wave P pad cols [144,160)
  u16* sPw = sP + wave * 16 * PSTR;
  for (int t = lane; t < 256; t += 64) {
    int rr = t >> 4, cc = 144 + (t & 15);
    sPw[rr * PSTR + cc] = 0;
  }

  asm volatile("s_waitcnt vmcnt(0)");   // sVT (and q/k) landed
  __syncthreads();

  f32x4 o[3][2];
#pragma unroll
  for (int mt = 0; mt < 3; mt++)
#pragma unroll
    for (int nt = 0; nt < 2; nt++) o[mt][nt] = fzero;

#pragma unroll
  for (int mt = 0; mt < 3; mt++) {
    f32x4 s[9];
#pragma unroll
    for (int nt = 0; nt < 9; nt++) s[nt] = MFMA16(qa[mt], kb[nt], fzero);

#pragma unroll
    for (int r = 0; r < 4; r++) {
      float p[9], sum = 0.f;
#pragma unroll
      for (int nt = 0; nt < 9; nt++) {
        p[nt] = exp2f(s[nt][r] * SC2);
        sum += p[nt];
      }
#pragma unroll
      for (int off = 1; off < 16; off <<= 1) sum += __shfl_xor(sum, off, 64);
      float inv = 1.f / sum;
      int prow = lhi * 4 + r;
#pragma unroll
      for (int nt = 0; nt < 9; nt++)
        sPw[prow * PSTR + nt * 16 + l15] = f2b(p[nt] * inv);
    }

    // O[mt] = P V^T-read : K padded to 160 (5 MFMA steps)
#pragma unroll
    for (int kk = 0; kk < 5; kk++) {
      short8 pa = *reinterpret_cast<const short8*>(sPw + l15 * PSTR + kk * 32 + lhi * 8);
#pragma unroll
      for (int nt = 0; nt < 2; nt++) {
        short8 vb = *reinterpret_cast<const short8*>(sVT + (nt * 16 + l15) * VSTR + kk * 32 + lhi * 8);
        o[mt][nt] = MFMA16(pa, vb, o[mt][nt]);
      }
    }
  }

  const int rowb = win * 144 + wave * 48;
#pragma unroll
  for (int mt = 0; mt < 3; mt++) {
#pragma unroll
    for (int nt = 0; nt < 2; nt++) {
      int col = head * 32 + nt * 16 + l15;
#pragma unroll
      for (int r = 0; r < 4; r++) {
        int row = rowb + mt * 16 + lhi * 4 + r;
        outb[(size_t)row * 512 + col] = f2b(o[mt][nt][r]);
      }
    }
  }
}

// ---------------- launch ----------------
extern "C" void kernel_launch(void* const* d_in, const int* in_sizes, int n_in,
                              void* d_out, int out_size, void* d_ws, size_t ws_size,
                              hipStream_t stream) {
  const float* x      = (const float*)d_in[0];
  const float* qkv_w  = (const float*)d_in[1];
  const float* qkv_b  = (const float*)d_in[2];
  const float* proj_w = (const float*)d_in[3];
  const float* proj_b = (const float*)d_in[4];
  float* out = (float*)d_out;

  u16* xw     = (u16*)d_ws;                                 // 18432*512
  u16* qkvT   = xw + (size_t)18432 * 512;                   // 1536*512
  u16* projT  = qkvT + (size_t)1536 * 512;                  // 512*512
  u16* qkvs   = projT + (size_t)512 * 512;                  // 2*QTOT + 2048*VWH
  u16* attno  = qkvs + 2 * QTOT + (size_t)2048 * VWH;       // 18432*512

  prep_x_kernel<<<4608, 256, 0, stream>>>(x, xw);
  prep_wt_kernel<<<384, 256, 0, stream>>>(qkv_w, qkvT, 512, 1536);
  prep_wt_kernel<<<128, 256, 0, stream>>>(proj_w, projT, 512, 512);
  pad_clear_kernel<<<2048, 128, 0, stream>>>(qkvs + 2 * QTOT);

  // QKV: 128^2 tile, grid 144*12=1728 (%8==0), scatter epilogue
  qkv_gemm<<<1728, 256, 0, stream>>>(xw, qkvT, qkv_b, qkvs, 18432, 1536, 512);

  attn_kernel<<<2048, 192, 0, stream>>>(qkvs, attno);

  // proj: 128^2 tile, grid 144*4=576 (%8==0), window_reverse epilogue
  proj_gemm<<<576, 256, 0, stream>>>(attno, projT, proj_b, out, 18432, 512, 512);
}

// Round 9
// 205.841 us; speedup vs baseline: 1.0561x; 1.0561x over previous
//
#include <hip/hip_runtime.h>
#include <hip/hip_bf16.h>

// Florence2VisionWindowAttention on MI355X (gfx950), bf16-MFMA pipeline.
// R8 == R7 resubmit (R7 bench failed on GPU acquisition; no data).
// R7: QKV back to R4's proven 256^2 4-slot ring / prefetch-3 / counted vmcnt
//     (46us measured) + attn-layout scatter epilogue (V^T via short4 stores).
//     proj back to R4's 128^2 ring-4 (launch_bounds(256,2), no VGPR squeeze).
//     attn v2 (coalesced Q/K, V^T staged by global_load_lds) kept.

typedef unsigned short u16;
typedef unsigned int u32;
typedef __attribute__((ext_vector_type(4))) float f32x4;
typedef __attribute__((ext_vector_type(4))) short short4v;
typedef __attribute__((ext_vector_type(8))) short short8;

#define MFMA16(a, b, c) __builtin_amdgcn_mfma_f32_16x16x32_bf16(a, b, c, 0, 0, 0)
#define AS1 __attribute__((address_space(1)))
#define AS3 __attribute__((address_space(3)))

constexpr size_t QTOT = (size_t)2048 * 4608;   // Q region elems (= K region)
constexpr int VSTR = 176;                      // V^T row stride (u16)
constexpr size_t VWH = 32 * VSTR;              // V^T elems per (win,head)

__device__ __forceinline__ u16 f2b(float f) {
  __hip_bfloat16 h = __float2bfloat16(f);
  return *reinterpret_cast<u16*>(&h);
}

// ---------------- prep: gather x into window order + fp32->bf16 ----------------
__global__ void prep_x_kernel(const float* __restrict__ x, u16* __restrict__ xw) {
  int c = blockIdx.x * 256 + threadIdx.x;
  int r = c >> 6;
  int colb = (c & 63) << 3;
  int win = r / 144, tok = r - win * 144;
  int b = win >> 4, wh = (win >> 2) & 3, ww = win & 3;
  int i = tok / 12, j = tok - i * 12;
  const float* src = x + ((size_t)((b * 48 + wh * 12 + i) * 48 + ww * 12 + j)) * 512 + colb;
  float4 a0 = *(const float4*)(src);
  float4 a1 = *(const float4*)(src + 4);
  short8 o;
  o[0] = (short)f2b(a0.x); o[1] = (short)f2b(a0.y); o[2] = (short)f2b(a0.z); o[3] = (short)f2b(a0.w);
  o[4] = (short)f2b(a1.x); o[5] = (short)f2b(a1.y); o[6] = (short)f2b(a1.z); o[7] = (short)f2b(a1.w);
  *reinterpret_cast<short8*>(xw + (size_t)r * 512 + colb) = o;
}

// ---------------- prep: weight transpose K x N -> N x K bf16 ----------------
__global__ void prep_wt_kernel(const float* __restrict__ w, u16* __restrict__ wt,
                               int K, int N) {
  int t = blockIdx.x * 256 + threadIdx.x;
  int nchunks = N >> 3;
  if (t >= K * nchunks) return;
  int k = t / nchunks;
  int n0 = (t - k * nchunks) << 3;
  const float* src = w + (size_t)k * N + n0;
  float4 a0 = *(const float4*)(src);
  float4 a1 = *(const float4*)(src + 4);
  float v[8] = {a0.x, a0.y, a0.z, a0.w, a1.x, a1.y, a1.z, a1.w};
#pragma unroll
  for (int j = 0; j < 8; j++) wt[(size_t)(n0 + j) * K + k] = f2b(v[j]);
}

// ---------------- pad_clear: zero V^T pad cols [144,176) ----------------
__global__ void pad_clear_kernel(u16* __restrict__ vs) {
  int wh = blockIdx.x;
  int t = threadIdx.x;            // 128 threads
  int d = t >> 2, c = 144 + (t & 3) * 8;
  short8 z = {0, 0, 0, 0, 0, 0, 0, 0};
  *reinterpret_cast<short8*>(vs + (size_t)wh * VWH + d * VSTR + c) = z;
}

// ---------------- GEMM core: C = A(MxK) * BT(NxK)^T + bias ----------------
// WM x WN waves, per-wave (BM/WM) x (BN/WN). BK=32, 4-slot ring, prefetch 3,
// counted vmcnt(8)->4->0 gates. Per K-tile body (R4 ordering):
//   gate+barrier -> ALL frag ds_reads -> [fence] -> stage t+3 -> [fence] ->
//   setprio(1) MFMA cluster setprio(0) -> barrier.
// Swizzle: linear 16B-slot = logical ^ ((row>>1)&3); staged via pre-swizzled
// global source (global_load_lds writes linearly), read with same XOR.
// EPI: 0 = bf16 row-major; 1 = fp32 + window_reverse; 2 = QKV scatter to
//      Q[wh][tok][32], K[wh][tok][32], V^T[wh][d][176] (V via short4).
template <int BM, int BN, int WM, int WN, int EPI>
__device__ __forceinline__ void gemm_impl(
    const u16* __restrict__ A, const u16* __restrict__ BT,
    const float* __restrict__ bias,
    u16* __restrict__ outb, float* __restrict__ outf,
    int M, int N, int K) {
  constexpr int MF = BM / WM / 16;
  constexpr int NF = BN / WN / 16;
  constexpr int ASLOT = BM * 32;
  constexpr int BSLOT = BN * 32;
  __shared__ __align__(16) u16 sA[4 * ASLOT];
  __shared__ __align__(16) u16 sB[4 * BSLOT];

  const int tid = threadIdx.x;
  const int wave = tid >> 6;
  const int lane = tid & 63;
  const int wm = wave / WN;
  const int wn = wave % WN;
  const int l15 = lane & 15;
  const int lhi = lane >> 4;

  // XCD-bijective block swizzle (grid % 8 == 0 for all our launches)
  const int nwg = gridDim.x;
  const int cpx = nwg >> 3;
  const int bid = (blockIdx.x & 7) * cpx + (blockIdx.x >> 3);
  const int nbn = N / BN;
  const int bn = bid % nbn;
  const int bm = bid / nbn;

  f32x4 acc[MF][NF];
  const f32x4 fzero = {0.f, 0.f, 0.f, 0.f};
#pragma unroll
  for (int i = 0; i < MF; i++)
#pragma unroll
    for (int j = 0; j < NF; j++) acc[i][j] = fzero;

  const int srow = lane >> 2;                                // row in 16-row chunk
  const int scol = (((lane & 3) ^ ((lane >> 3) & 3)) << 3);  // pre-swizzled col
  const int rcol = ((lhi ^ ((l15 >> 1) & 3)) << 3);          // swizzled read col

  const u16* Ab = A + (size_t)(bm * BM) * K;
  const u16* Bb = BT + (size_t)(bn * BN) * K;
  const int nt = K >> 5;

  auto stage = [&](int l, int tt) {
    const int slot = tt & 3;
    const int kk = tt << 5;
    if (l < 2) {
      const int c = wave * 2 + l;
      __builtin_amdgcn_global_load_lds(
          (const AS1 u32*)(Ab + (size_t)(c * 16 + srow) * K + kk + scol),
          (AS3 u32*)(&sA[slot * ASLOT + c * 512]), 16, 0, 0);
    } else {
      const int c = wave * 2 + (l - 2);
      __builtin_amdgcn_global_load_lds(
          (const AS1 u32*)(Bb + (size_t)(c * 16 + srow) * K + kk + scol),
          (AS3 u32*)(&sB[slot * BSLOT + c * 512]), 16, 0, 0);
    }
  };

  // prologue: stage tiles 0,1,2 (tile-major issue order for vmcnt counting)
#pragma unroll
  for (int t0 = 0; t0 < 3; ++t0)
#pragma unroll
    for (int l = 0; l < 4; ++l) stage(l, t0);

  for (int t = 0; t < nt; ++t) {
    const int cur = t & 3;
    const bool has3 = (t + 3 < nt);
    const int rem = nt - 1 - t;

    if (rem >= 2)      { asm volatile("s_waitcnt vmcnt(8)"); }
    else if (rem == 1) { asm volatile("s_waitcnt vmcnt(4)"); }
    else               { asm volatile("s_waitcnt vmcnt(0)"); }
    __builtin_amdgcn_sched_barrier(0);
    __builtin_amdgcn_s_barrier();
    __builtin_amdgcn_sched_barrier(0);

    const u16* pA = &sA[cur * ASLOT];
    const u16* pB = &sB[cur * BSLOT];

    // 1) ALL fragment ds_reads for this K-tile, pinned before any staging
    short8 af[MF], bfr[NF];
#pragma unroll
    for (int m = 0; m < MF; ++m)
      af[m] = *reinterpret_cast<const short8*>(
          pA + (wm * (MF * 16) + m * 16 + l15) * 32 + rcol);
#pragma unroll
    for (int n = 0; n < NF; ++n)
      bfr[n] = *reinterpret_cast<const short8*>(
          pB + (wn * (NF * 16) + n * 16 + l15) * 32 + rcol);
    __builtin_amdgcn_sched_barrier(0);

    // 2) stage tile t+3
    if (has3) {
#pragma unroll
      for (int l = 0; l < 4; ++l) stage(l, t + 3);
    }
    __builtin_amdgcn_sched_barrier(0);

    // 3) MFMA cluster
    __builtin_amdgcn_s_setprio(1);
#pragma unroll
    for (int m = 0; m < MF; ++m)
#pragma unroll
      for (int n = 0; n < NF; ++n)
        acc[m][n] = MFMA16(af[m], bfr[n], acc[m][n]);
    __builtin_amdgcn_s_setprio(0);

    __builtin_amdgcn_sched_barrier(0);
    __builtin_amdgcn_s_barrier();   // all waves done reading slot cur
  }

  // epilogue
#pragma unroll
  for (int i = 0; i < MF; ++i) {
    const int row0 = bm * BM + wm * (MF * 16) + i * 16 + lhi * 4;
#pragma unroll
    for (int j = 0; j < NF; ++j) {
      const int col = bn * BN + wn * (NF * 16) + j * 16 + l15;
      const float bv = bias[col];
      if (EPI == 2 && (col >> 9) == 2) {
        // V: pack 4 consecutive toks into one short4 store
        int d = col & 31;
        int head = (col & 511) >> 5;
        int win = row0 / 144, tok = row0 - win * 144;   // 4-aligned, same win
        int wh = win * 16 + head;
        short4v pv;
#pragma unroll
        for (int r = 0; r < 4; ++r) pv[r] = (short)f2b(acc[i][j][r] + bv);
        *reinterpret_cast<short4v*>(outb + 2 * QTOT + (size_t)wh * VWH + d * VSTR + tok) = pv;
      } else {
#pragma unroll
        for (int r = 0; r < 4; ++r) {
          float v = acc[i][j][r] + bv;
          const int row = row0 + r;
          if (EPI == 0) {
            outb[(size_t)row * N + col] = f2b(v);
          } else if (EPI == 1) {
            int win = row / 144, tok = row - win * 144;
            int b = win >> 4, wh = (win >> 2) & 3, ww = win & 3;
            int ii = tok / 12, jj = tok - ii * 12;
            size_t o = ((size_t)b * 2304 + (wh * 12 + ii) * 48 + (ww * 12 + jj)) * 512 + col;
            outf[o] = v;
          } else {
            int dg = col & 511;
            int typ = col >> 9;
            int head = dg >> 5, d = dg & 31;
            int win = row / 144, tok = row - win * 144;
            int wh = win * 16 + head;
            u16 bv16 = f2b(v);
            if (typ == 0)
              outb[(size_t)wh * 4608 + tok * 32 + d] = bv16;
            else
              outb[QTOT + (size_t)wh * 4608 + tok * 32 + d] = bv16;
          }
        }
      }
    }
  }
}

__global__ __launch_bounds__(512, 1) void qkv_gemm(
    const u16* __restrict__ A, const u16* __restrict__ BT,
    const float* __restrict__ bias, u16* __restrict__ outb,
    int M, int N, int K) {
  gemm_impl<256, 256, 2, 4, 2>(A, BT, bias, outb, nullptr, M, N, K);
}

__global__ __launch_bounds__(256, 2) void proj_gemm(
    const u16* __restrict__ A, const u16* __restrict__ BT,
    const float* __restrict__ bias, float* __restrict__ outf,
    int M, int N, int K) {
  gemm_impl<128, 128, 2, 2, 1>(A, BT, bias, nullptr, outf, M, N, K);
}

// ---------------- fused window attention v2 ----------------
// One block per (win,head) = wh, 192 threads = 3 waves, 48 q-rows/wave.
// Q,K read coalesced from [wh][tok][32]; V^T staged via global_load_lds
// from [wh][32][176] (pads pre-zeroed). No-max softmax.
__global__ __launch_bounds__(192) void attn_kernel(const u16* __restrict__ qkvs,
                                                   u16* __restrict__ outb) {
  constexpr int PSTR = 168;
  __shared__ __align__(16) u16 sVT[32 * VSTR];      // 11264 B
  __shared__ __align__(16) u16 sP[3 * 16 * PSTR];
  const int tid = threadIdx.x;
  const int wave = tid >> 6;
  const int lane = tid & 63;
  const int l15 = lane & 15;
  const int lhi = lane >> 4;
  const int wh = blockIdx.x;
  const int win = wh >> 4;
  const int head = wh & 15;
  const u16* Q = qkvs + (size_t)wh * 4608;
  const u16* Kp = qkvs + QTOT + (size_t)wh * 4608;
  const u16* V = qkvs + 2 * QTOT + (size_t)wh * VWH;
  constexpr float SC2 = 0.25509915922608635f;       // (1/sqrt(32)) * log2(e)
  const f32x4 fzero = {0.f, 0.f, 0.f, 0.f};

  // stage V^T (32x176 u16 = 11 KB) linearly: 11 wave-instrs of 1KB
#pragma unroll
  for (int i = 0; i < 4; ++i) {
    const int c = wave * 4 + i;                     // wave-uniform
    if (c < 11) {
      __builtin_amdgcn_global_load_lds(
          (const AS1 u32*)(V + c * 512 + lane * 8),
          (AS3 u32*)(&sVT[c * 512]), 16, 0, 0);
    }
  }

  // coalesced Q/K fragment loads
  short8 qa[3];
#pragma unroll
  for (int mt = 0; mt < 3; mt++) {
    int row = wave * 48 + mt * 16 + l15;
    qa[mt] = *reinterpret_cast<const short8*>(Q + row * 32 + lhi * 8);
  }
  short8 kb[9];
#pragma unroll
  for (int nt = 0; nt < 9; nt++) {
    int ctok = nt * 16 + l15;
    kb[nt] = *reinterpret_cast<const short8*>(Kp + ctok * 32 + lhi * 8);
  }

  // zero own-wave P pad cols [144,160)
  u16* sPw = sP + wave * 16 * PSTR;
  for (int t = lane; t < 256; t += 64) {
    int rr = t >> 4, cc = 144 + (t & 15);
    sPw[rr * PSTR + cc] = 0;
  }

  asm volatile("s_waitcnt vmcnt(0)");   // sVT (and q/k) landed
  __syncthreads();

  f32x4 o[3][2];
#pragma unroll
  for (int mt = 0; mt < 3; mt++)
#pragma unroll
    for (int nt = 0; nt < 2; nt++) o[mt][nt] = fzero;

#pragma unroll
  for (int mt = 0; mt < 3; mt++) {
    f32x4 s[9];
#pragma unroll
    for (int nt = 0; nt < 9; nt++) s[nt] = MFMA16(qa[mt], kb[nt], fzero);

#pragma unroll
    for (int r = 0; r < 4; r++) {
      float p[9], sum = 0.f;
#pragma unroll
      for (int nt = 0; nt < 9; nt++) {
        p[nt] = exp2f(s[nt][r] * SC2);
        sum += p[nt];
      }
#pragma unroll
      for (int off = 1; off < 16; off <<= 1) sum += __shfl_xor(sum, off, 64);
      float inv = 1.f / sum;
      int prow = lhi * 4 + r;
#pragma unroll
      for (int nt = 0; nt < 9; nt++)
        sPw[prow * PSTR + nt * 16 + l15] = f2b(p[nt] * inv);
    }

    // O[mt] = P V^T-read : K padded to 160 (5 MFMA steps)
#pragma unroll
    for (int kk = 0; kk < 5; kk++) {
      short8 pa = *reinterpret_cast<const short8*>(sPw + l15 * PSTR + kk * 32 + lhi * 8);
#pragma unroll
      for (int nt = 0; nt < 2; nt++) {
        short8 vb = *reinterpret_cast<const short8*>(sVT + (nt * 16 + l15) * VSTR + kk * 32 + lhi * 8);
        o[mt][nt] = MFMA16(pa, vb, o[mt][nt]);
      }
    }
  }

  const int rowb = win * 144 + wave * 48;
#pragma unroll
  for (int mt = 0; mt < 3; mt++) {
#pragma unroll
    for (int nt = 0; nt < 2; nt++) {
      int col = head * 32 + nt * 16 + l15;
#pragma unroll
      for (int r = 0; r < 4; r++) {
        int row = rowb + mt * 16 + lhi * 4 + r;
        outb[(size_t)row * 512 + col] = f2b(o[mt][nt][r]);
      }
    }
  }
}

// ---------------- launch ----------------
extern "C" void kernel_launch(void* const* d_in, const int* in_sizes, int n_in,
                              void* d_out, int out_size, void* d_ws, size_t ws_size,
                              hipStream_t stream) {
  const float* x      = (const float*)d_in[0];
  const float* qkv_w  = (const float*)d_in[1];
  const float* qkv_b  = (const float*)d_in[2];
  const float* proj_w = (const float*)d_in[3];
  const float* proj_b = (const float*)d_in[4];
  float* out = (float*)d_out;

  u16* xw     = (u16*)d_ws;                                 // 18432*512
  u16* qkvT   = xw + (size_t)18432 * 512;                   // 1536*512
  u16* projT  = qkvT + (size_t)1536 * 512;                  // 512*512
  u16* qkvs   = projT + (size_t)512 * 512;                  // 2*QTOT + 2048*VWH
  u16* attno  = qkvs + 2 * QTOT + (size_t)2048 * VWH;       // 18432*512

  prep_x_kernel<<<4608, 256, 0, stream>>>(x, xw);
  prep_wt_kernel<<<384, 256, 0, stream>>>(qkv_w, qkvT, 512, 1536);
  prep_wt_kernel<<<128, 256, 0, stream>>>(proj_w, projT, 512, 512);
  pad_clear_kernel<<<2048, 128, 0, stream>>>(qkvs + 2 * QTOT);

  // QKV: 256^2 tile, grid 72*6=432 (%8==0), scatter epilogue
  qkv_gemm<<<432, 512, 0, stream>>>(xw, qkvT, qkv_b, qkvs, 18432, 1536, 512);

  attn_kernel<<<2048, 192, 0, stream>>>(qkvs, attno);

  // proj: 128^2 tile, grid 144*4=576 (%8==0), window_reverse epilogue
  proj_gemm<<<576, 256, 0, stream>>>(attno, projT, proj_b, out, 18432, 512, 512);
}